// Round 7
// baseline (194.449 us; speedup 1.0000x reference)
//
#include <hip/hip_runtime.h>
#include <stdint.h>

#define LOG2_HASHMAP_SIZE 19
#define HASHTABLE_SIZE (1u << LOG2_HASHMAP_SIZE)
#define HASHTABLE_MASK (HASHTABLE_SIZE - 1u)
#define RES_F 128.0f

typedef float f32x2 __attribute__((ext_vector_type(2)));
typedef float f32x4 __attribute__((ext_vector_type(4)));
typedef uint32_t u32x2 __attribute__((ext_vector_type(2)));
typedef uint32_t u32x4 __attribute__((ext_vector_type(4)));
typedef int i32x4 __attribute__((ext_vector_type(4)));

// Raw buffer loads: SRD base lives in SGPRs -> 1 VGPR (voffset) per gather.
__device__ u32x2 llvm_amdgcn_raw_buffer_load_v2u32(i32x4 rsrc, int voffset,
                                                   int soffset, int aux)
    __asm("llvm.amdgcn.raw.buffer.load.v2i32");
__device__ uint32_t llvm_amdgcn_raw_buffer_load_u32(i32x4 rsrc, int voffset,
                                                    int soffset, int aux)
    __asm("llvm.amdgcn.raw.buffer.load.i32");

__device__ __forceinline__ i32x4 make_srd(const void* p, uint32_t bytes) {
    union { const void* p; uint32_t u[2]; } a;
    a.p = p;
    i32x4 r;
    r.x = (int)a.u[0];                 // base[31:0]
    r.y = (int)(a.u[1] & 0xFFFFu);     // base[47:32], stride=0
    r.z = (int)bytes;                  // num_records (bytes, stride==0)
    r.w = 0x00020000;                  // raw untyped dword access
    return r;
}

// Non-temporal for STREAMING traffic (x, out): evict-first in L2 so the
// 2 MiB bf16 hashtable stays L2-resident.
__device__ __forceinline__ f32x2 nt_load2(const f32x2* p) {
    return __builtin_nontemporal_load(p);
}
__device__ __forceinline__ void nt_store4(f32x4* p, f32x4 v) {
    __builtin_nontemporal_store(v, p);
}

__device__ __forceinline__ float bf16w_lo(uint32_t w) {
    return __uint_as_float(w << 16);
}
__device__ __forceinline__ float bf16w_hi(uint32_t w) {
    return __uint_as_float(w & 0xFFFF0000u);
}

// ---- Pass 1: convert fp32 table (float2/entry) -> bf16x2 (uint32/entry) ----
__device__ __forceinline__ uint32_t pack_bf16x2(float a, float b) {
    uint32_t ua = __float_as_uint(a);
    uint32_t ub = __float_as_uint(b);
    ua = ua + 0x7FFFu + ((ua >> 16) & 1u);   // RTNE
    ub = ub + 0x7FFFu + ((ub >> 16) & 1u);
    return (ua >> 16) | (ub & 0xFFFF0000u);
}

__global__ __launch_bounds__(256) void convert_table_kernel(
    const f32x4* __restrict__ table4,   // HASHTABLE_SIZE/2 float4 (2 entries each)
    u32x4* __restrict__ ws4)            // HASHTABLE_SIZE/4 uint4
{
    int i = blockIdx.x * blockDim.x + threadIdx.x;   // 1 uint4 = 4 entries
    f32x4 e01 = table4[2 * i + 0];
    f32x4 e23 = table4[2 * i + 1];
    u32x4 o;
    o.x = pack_bf16x2(e01.x, e01.y);
    o.y = pack_bf16x2(e01.z, e01.w);
    o.z = pack_bf16x2(e23.x, e23.y);
    o.w = pack_bf16x2(e23.z, e23.w);
    ws4[i] = o;
}

// ---- Pass 2: main kernel, 2 points per thread, WIDTH-ADAPTIVE gathers ----
// Hash = ix ^ iy*P1 ^ iz*P2; the x-corner pair differs by mm = fx^cx.
// mm<=1 (fx even OR dx==0, 50%): one 8-B load at (i0 & ~1) covers both
// corners. mm>1 (50%): the 8-B load covers the fx corner; one extra 4-B load
// fetches the cx corner. Requests/pt = 6, all <=8 B — tests whether the
// per-request cost is width-dependent (R2: 8B @2.15 cyc vs R6: 16B @~3 cyc).
__global__ __launch_bounds__(256, 8) void featurefield_bf16_kernel(
    const f32x2* __restrict__ x2,       // N/2 * 3 float2
    const uint32_t* __restrict__ tb,    // HASHTABLE_SIZE bf16x2 entries
    f32x4* __restrict__ out4,           // N/2 float4 (2 pts * 2 feats)
    int n_pairs)
{
    int t = blockIdx.x * blockDim.x + threadIdx.x;
    if (t >= n_pairs) return;

    i32x4 srd = make_srd(tb, HASHTABLE_SIZE * 4u);

    f32x2 A = nt_load2(&x2[3 * t + 0]);   // p0.x p0.y
    f32x2 B = nt_load2(&x2[3 * t + 1]);   // p0.z p1.x
    f32x2 C = nt_load2(&x2[3 * t + 2]);   // p1.y p1.z

    float px[2] = {A.x, B.y};
    float py[2] = {A.y, C.x};
    float pz[2] = {B.x, C.y};

    uint32_t i0[2][4];
    uint32_t mm[2];
    float dxs[2], dys[2], dzs[2];

    #pragma unroll
    for (int k = 0; k < 2; ++k) {
        float xs = px[k] * RES_F;
        float ys = py[k] * RES_F;
        float zs = pz[k] * RES_F;
        float fxf = floorf(xs), fyf = floorf(ys), fzf = floorf(zs);
        int fx = (int)fxf, fy = (int)fyf, fz = (int)fzf;
        int cx = (int)ceilf(xs), cy = (int)ceilf(ys), cz = (int)ceilf(zs);
        dxs[k] = xs - fxf;
        dys[k] = ys - fyf;
        dzs[k] = zs - fzf;

        uint32_t ufx = (uint32_t)fx;
        mm[k] = ufx ^ (uint32_t)cx;   // 0 (dx==0), 1 (fx even), 3,7,... 
        uint32_t fyp = (uint32_t)fy * 2654435761u;
        uint32_t cyp = (uint32_t)cy * 2654435761u;
        uint32_t fzp = (uint32_t)fz * 805459861u;
        uint32_t czp = (uint32_t)cz * 805459861u;

        i0[k][0] = (ufx ^ fyp ^ fzp) & HASHTABLE_MASK;  // (fy,fz)
        i0[k][1] = (ufx ^ cyp ^ fzp) & HASHTABLE_MASK;  // (cy,fz)
        i0[k][2] = (ufx ^ fyp ^ czp) & HASHTABLE_MASK;  // (fy,cz)
        i0[k][3] = (ufx ^ cyp ^ czp) & HASHTABLE_MASK;  // (cy,cz)
    }

    // Phase A: 8 always-loads (8 B each, 8B-aligned pair containing i0),
    // issued back-to-back for both points.
    u32x2 p[2][4];
    #pragma unroll
    for (int k = 0; k < 2; ++k) {
        #pragma unroll
        for (int j = 0; j < 4; ++j) {
            p[k][j] = llvm_amdgcn_raw_buffer_load_v2u32(
                srd, (int)((i0[k][j] << 2) & ~7u), 0, 0);
        }
    }

    // Phase B: conditional partner loads (mm>1, ~50% of points), issued
    // before any extraction so they overlap the always-loads.
    uint32_t w1[2][4];
    #pragma unroll
    for (int k = 0; k < 2; ++k) {
        if (mm[k] > 1u) {
            #pragma unroll
            for (int j = 0; j < 4; ++j) {
                w1[k][j] = llvm_amdgcn_raw_buffer_load_u32(
                    srd, (int)((i0[k][j] ^ mm[k]) << 2), 0, 0);
            }
        }
    }

    // Phase C: extraction. w0 from the pair; w1 from the pair when mm<=1
    // (covers mm==0: partner == self).
    uint32_t w0[2][4];
    #pragma unroll
    for (int k = 0; k < 2; ++k) {
        #pragma unroll
        for (int j = 0; j < 4; ++j) {
            uint32_t e0 = i0[k][j] & 1u;
            w0[k][j] = e0 ? p[k][j].y : p[k][j].x;
        }
        if (mm[k] <= 1u) {
            #pragma unroll
            for (int j = 0; j < 4; ++j) {
                uint32_t e1 = (i0[k][j] ^ mm[k]) & 1u;
                w1[k][j] = e1 ? p[k][j].y : p[k][j].x;
            }
        }
    }

    // Trilinear interpolation, reference ordering.
    f32x2 res[2];
    #pragma unroll
    for (int k = 0; k < 2; ++k) {
        float dx = dxs[k], dy = dys[k], dz = dzs[k];
        float wx = 1.0f - dx, wy = 1.0f - dy, wz = 1.0f - dz;

        // pair j: 0=(fy,fz) 1=(cy,fz) 2=(fy,cz) 3=(cy,cz); w0=fx, w1=cx
        float c00x = bf16w_lo(w0[k][0]) * wx + bf16w_lo(w1[k][0]) * dx;
        float c00y = bf16w_hi(w0[k][0]) * wx + bf16w_hi(w1[k][0]) * dx;
        float c10x = bf16w_lo(w0[k][1]) * wx + bf16w_lo(w1[k][1]) * dx;
        float c10y = bf16w_hi(w0[k][1]) * wx + bf16w_hi(w1[k][1]) * dx;
        float c01x = bf16w_lo(w0[k][2]) * wx + bf16w_lo(w1[k][2]) * dx;
        float c01y = bf16w_hi(w0[k][2]) * wx + bf16w_hi(w1[k][2]) * dx;
        float c11x = bf16w_lo(w0[k][3]) * wx + bf16w_lo(w1[k][3]) * dx;
        float c11y = bf16w_hi(w0[k][3]) * wx + bf16w_hi(w1[k][3]) * dx;

        float c0x = c00x * wy + c10x * dy;
        float c0y = c00y * wy + c10y * dy;
        float c1x = c01x * wy + c11x * dy;
        float c1y = c01y * wy + c11y * dy;

        res[k].x = c0x * wz + c1x * dz;
        res[k].y = c0y * wz + c1y * dz;
    }

    f32x4 o = {res[0].x, res[0].y, res[1].x, res[1].y};
    nt_store4(&out4[t], o);
}

// ---- Fallback (fp32 direct) if ws is too small ----
__global__ __launch_bounds__(256) void featurefield_fp32_kernel(
    const f32x2* __restrict__ x2,
    const float2* __restrict__ table,
    f32x4* __restrict__ out4,
    int n_pairs)
{
    int t = blockIdx.x * blockDim.x + threadIdx.x;
    if (t >= n_pairs) return;

    f32x2 A = nt_load2(&x2[3 * t + 0]);
    f32x2 B = nt_load2(&x2[3 * t + 1]);
    f32x2 C = nt_load2(&x2[3 * t + 2]);

    float px[2] = {A.x, B.y};
    float py[2] = {A.y, C.x};
    float pz[2] = {B.x, C.y};

    f32x2 res[2];
    #pragma unroll
    for (int k = 0; k < 2; ++k) {
        float xs = px[k] * RES_F, ys = py[k] * RES_F, zs = pz[k] * RES_F;
        float fxf = floorf(xs), fyf = floorf(ys), fzf = floorf(zs);
        int fx = (int)fxf, fy = (int)fyf, fz = (int)fzf;
        int cx = (int)ceilf(xs), cy = (int)ceilf(ys), cz = (int)ceilf(zs);
        float dx = xs - fxf, dy = ys - fyf, dz = zs - fzf;
        uint32_t ufx = (uint32_t)fx, ucx = (uint32_t)cx;
        uint32_t fyp = (uint32_t)fy * 2654435761u, cyp = (uint32_t)cy * 2654435761u;
        uint32_t fzp = (uint32_t)fz * 805459861u, czp = (uint32_t)cz * 805459861u;
        uint32_t h0 = (ufx ^ fyp ^ fzp) & HASHTABLE_MASK;
        uint32_t h1 = (ucx ^ fyp ^ fzp) & HASHTABLE_MASK;
        uint32_t h2 = (ufx ^ cyp ^ fzp) & HASHTABLE_MASK;
        uint32_t h3 = (ufx ^ fyp ^ czp) & HASHTABLE_MASK;
        uint32_t h4 = (ucx ^ cyp ^ fzp) & HASHTABLE_MASK;
        uint32_t h5 = (ucx ^ fyp ^ czp) & HASHTABLE_MASK;
        uint32_t h6 = (ufx ^ cyp ^ czp) & HASHTABLE_MASK;
        uint32_t h7 = (ucx ^ cyp ^ czp) & HASHTABLE_MASK;

        float2 v0 = table[h0], v1 = table[h1], v2 = table[h2], v3 = table[h3];
        float2 v4 = table[h4], v5 = table[h5], v6 = table[h6], v7 = table[h7];

        float wx = 1.0f - dx, wy = 1.0f - dy, wz = 1.0f - dz;
        float c00x = v0.x * wx + v1.x * dx, c00y = v0.y * wx + v1.y * dx;
        float c01x = v3.x * wx + v5.x * dx, c01y = v3.y * wx + v5.y * dx;
        float c10x = v2.x * wx + v4.x * dx, c10y = v2.y * wx + v4.y * dx;
        float c11x = v6.x * wx + v7.x * dx, c11y = v6.y * wx + v7.y * dx;
        float c0x = c00x * wy + c10x * dy, c0y = c00y * wy + c10y * dy;
        float c1x = c01x * wy + c11x * dy, c1y = c01y * wy + c11y * dy;
        res[k].x = c0x * wz + c1x * dz;
        res[k].y = c0y * wz + c1y * dz;
    }

    f32x4 o = {res[0].x, res[0].y, res[1].x, res[1].y};
    nt_store4(&out4[t], o);
}

extern "C" void kernel_launch(void* const* d_in, const int* in_sizes, int n_in,
                              void* d_out, int out_size, void* d_ws, size_t ws_size,
                              hipStream_t stream) {
    const f32x2* x2 = (const f32x2*)d_in[0];
    f32x4* out4 = (f32x4*)d_out;

    int n_points = in_sizes[0] / 3;   // 4194304
    int n_pairs = n_points / 2;       // 2097152
    int block = 256;
    int grid = (n_pairs + block - 1) / block;  // 8192

    size_t need = (size_t)HASHTABLE_SIZE * 4u;   // 2 MiB bf16 table
    if (ws_size >= need) {
        const f32x4* table4 = (const f32x4*)d_in[1];
        u32x4* ws4 = (u32x4*)d_ws;
        int conv_threads = HASHTABLE_SIZE / 4;   // 131072
        convert_table_kernel<<<conv_threads / 256, 256, 0, stream>>>(table4, ws4);
        featurefield_bf16_kernel<<<grid, block, 0, stream>>>(
            x2, (const uint32_t*)d_ws, out4, n_pairs);
    } else {
        const float2* table = (const float2*)d_in[1];
        featurefield_fp32_kernel<<<grid, block, 0, stream>>>(x2, table, out4, n_pairs);
    }
}

// Round 8
// 179.848 us; speedup vs baseline: 1.0812x; 1.0812x over previous
//
#include <hip/hip_runtime.h>
#include <stdint.h>

#define LOG2_HASHMAP_SIZE 19
#define HASHTABLE_SIZE (1u << LOG2_HASHMAP_SIZE)
#define HASHTABLE_MASK (HASHTABLE_SIZE - 1u)
#define RES_F 128.0f

typedef float f32x2 __attribute__((ext_vector_type(2)));
typedef float f32x4 __attribute__((ext_vector_type(4)));
typedef uint32_t u32x4 __attribute__((ext_vector_type(4)));
typedef int i32x4 __attribute__((ext_vector_type(4)));

// Raw buffer loads: SRD base in SGPRs -> 1 VGPR (voffset) per gather.
__device__ u32x4 llvm_amdgcn_raw_buffer_load_v4u32(i32x4 rsrc, int voffset,
                                                   int soffset, int aux)
    __asm("llvm.amdgcn.raw.buffer.load.v4i32");
__device__ uint32_t llvm_amdgcn_raw_buffer_load_u32(i32x4 rsrc, int voffset,
                                                    int soffset, int aux)
    __asm("llvm.amdgcn.raw.buffer.load.i32");

__device__ __forceinline__ i32x4 make_srd(const void* p, uint32_t bytes) {
    union { const void* p; uint32_t u[2]; } a;
    a.p = p;
    i32x4 r;
    r.x = (int)a.u[0];                 // base[31:0]
    r.y = (int)(a.u[1] & 0xFFFFu);     // base[47:32], stride=0
    r.z = (int)bytes;                  // num_records (bytes, stride==0)
    r.w = 0x00020000;                  // raw untyped dword access
    return r;
}

__device__ __forceinline__ float bf16w_lo(uint32_t w) {
    return __uint_as_float(w << 16);
}
__device__ __forceinline__ float bf16w_hi(uint32_t w) {
    return __uint_as_float(w & 0xFFFF0000u);
}

// Select one of 4 packed words by 2-bit index (explicit cndmask chain).
__device__ __forceinline__ uint32_t sel4(u32x4 q, uint32_t e) {
    uint32_t lo = (e & 1u) ? q.y : q.x;
    uint32_t hi = (e & 1u) ? q.w : q.z;
    return (e & 2u) ? hi : lo;
}

// ---- Pass 1: convert fp32 table (float2/entry) -> bf16x2 (uint32/entry) ----
__device__ __forceinline__ uint32_t pack_bf16x2(float a, float b) {
    uint32_t ua = __float_as_uint(a);
    uint32_t ub = __float_as_uint(b);
    ua = ua + 0x7FFFu + ((ua >> 16) & 1u);   // RTNE
    ub = ub + 0x7FFFu + ((ub >> 16) & 1u);
    return (ua >> 16) | (ub & 0xFFFF0000u);
}

__global__ __launch_bounds__(256) void convert_table_kernel(
    const f32x4* __restrict__ table4,   // HASHTABLE_SIZE/2 float4 (2 entries each)
    u32x4* __restrict__ ws4)            // HASHTABLE_SIZE/4 uint4
{
    int i = blockIdx.x * blockDim.x + threadIdx.x;   // 1 uint4 = 4 entries
    f32x4 e01 = table4[2 * i + 0];
    f32x4 e23 = table4[2 * i + 1];
    u32x4 o;
    o.x = pack_bf16x2(e01.x, e01.y);
    o.y = pack_bf16x2(e01.z, e01.w);
    o.z = pack_bf16x2(e23.x, e23.y);
    o.w = pack_bf16x2(e23.z, e23.w);
    ws4[i] = o;
}

// ---- Pass 2: software-pipelined main kernel ----
// R6 gather algorithm (4x16B + conditional partner, 5 txns/pt expected) but
// each thread handles 4 points at stride NT in a static 2-deep pipeline:
//   issue(p0); issue(p1); consume(p0); issue(p2); consume(p1); issue(p3);
//   consume(p2); consume(p3)
// so gathers for generation i+1/i+2 are in flight while generation i is
// extracted/interpolated — sustained outstanding requests instead of the
// R6 batch-drain duty cycle (the ~20% gap to the txn-rate floor).

struct Gen {
    u32x4 q[4];        // 16 VGPRs: 16-B granule per yz-pair
    uint32_t w1[4];    // partner words (valid when mm > 3)
    uint32_t i0[4];    // fx-corner entry index per yz-pair
    uint32_t mm;       // x-pair xor
    float dx, dy, dz;
};

__device__ __forceinline__ Gen issue_point(const float* __restrict__ x,
                                           i32x4 srd, int p) {
    Gen g;
    float xs = __builtin_nontemporal_load(x + 3 * p + 0) * RES_F;
    float ys = __builtin_nontemporal_load(x + 3 * p + 1) * RES_F;
    float zs = __builtin_nontemporal_load(x + 3 * p + 2) * RES_F;
    float fxf = floorf(xs), fyf = floorf(ys), fzf = floorf(zs);
    int fx = (int)fxf, fy = (int)fyf, fz = (int)fzf;
    int cx = (int)ceilf(xs), cy = (int)ceilf(ys), cz = (int)ceilf(zs);
    g.dx = xs - fxf;
    g.dy = ys - fyf;
    g.dz = zs - fzf;

    uint32_t ufx = (uint32_t)fx;
    g.mm = ufx ^ (uint32_t)cx;
    uint32_t fyp = (uint32_t)fy * 2654435761u;
    uint32_t cyp = (uint32_t)cy * 2654435761u;
    uint32_t fzp = (uint32_t)fz * 805459861u;
    uint32_t czp = (uint32_t)cz * 805459861u;

    g.i0[0] = (ufx ^ fyp ^ fzp) & HASHTABLE_MASK;  // (fy,fz)
    g.i0[1] = (ufx ^ cyp ^ fzp) & HASHTABLE_MASK;  // (cy,fz)
    g.i0[2] = (ufx ^ fyp ^ czp) & HASHTABLE_MASK;  // (fy,cz)
    g.i0[3] = (ufx ^ cyp ^ czp) & HASHTABLE_MASK;  // (cy,cz)

    #pragma unroll
    for (int j = 0; j < 4; ++j) {
        g.q[j] = llvm_amdgcn_raw_buffer_load_v4u32(
            srd, (int)((g.i0[j] << 2) & ~15u), 0, 0);
    }
    if (g.mm > 3u) {
        #pragma unroll
        for (int j = 0; j < 4; ++j) {
            g.w1[j] = llvm_amdgcn_raw_buffer_load_u32(
                srd, (int)((g.i0[j] ^ g.mm) << 2), 0, 0);
        }
    }
    return g;
}

__device__ __forceinline__ f32x2 consume_point(const Gen& g) {
    uint32_t w0[4], w1[4];
    #pragma unroll
    for (int j = 0; j < 4; ++j) {
        uint32_t e0 = g.i0[j] & 3u;
        w0[j] = sel4(g.q[j], e0);
        w1[j] = (g.mm <= 3u) ? sel4(g.q[j], e0 ^ g.mm) : g.w1[j];
    }

    float dx = g.dx, dy = g.dy, dz = g.dz;
    float wx = 1.0f - dx, wy = 1.0f - dy, wz = 1.0f - dz;

    // pair j: 0=(fy,fz) 1=(cy,fz) 2=(fy,cz) 3=(cy,cz); w0=fx, w1=cx
    float c00x = bf16w_lo(w0[0]) * wx + bf16w_lo(w1[0]) * dx;
    float c00y = bf16w_hi(w0[0]) * wx + bf16w_hi(w1[0]) * dx;
    float c10x = bf16w_lo(w0[1]) * wx + bf16w_lo(w1[1]) * dx;
    float c10y = bf16w_hi(w0[1]) * wx + bf16w_hi(w1[1]) * dx;
    float c01x = bf16w_lo(w0[2]) * wx + bf16w_lo(w1[2]) * dx;
    float c01y = bf16w_hi(w0[2]) * wx + bf16w_hi(w1[2]) * dx;
    float c11x = bf16w_lo(w0[3]) * wx + bf16w_lo(w1[3]) * dx;
    float c11y = bf16w_hi(w0[3]) * wx + bf16w_hi(w1[3]) * dx;

    float c0x = c00x * wy + c10x * dy;
    float c0y = c00y * wy + c10y * dy;
    float c1x = c01x * wy + c11x * dy;
    float c1y = c01y * wy + c11y * dy;

    f32x2 r;
    r.x = c0x * wz + c1x * dz;
    r.y = c0y * wz + c1y * dz;
    return r;
}

__device__ __forceinline__ void store_out(f32x2* __restrict__ out, int p,
                                          f32x2 v) {
    __builtin_nontemporal_store(v, out + p);
}

__global__ __launch_bounds__(256) void featurefield_pipe_kernel(
    const float* __restrict__ x,        // N*3 floats
    const uint32_t* __restrict__ tb,    // HASHTABLE_SIZE bf16x2 entries
    f32x2* __restrict__ out,            // N float2
    int NT)                             // stride = n_points/4
{
    int t = blockIdx.x * blockDim.x + threadIdx.x;
    if (t >= NT) return;

    i32x4 srd = make_srd(tb, HASHTABLE_SIZE * 4u);

    Gen g0 = issue_point(x, srd, t);
    Gen g1 = issue_point(x, srd, t + NT);
    store_out(out, t, consume_point(g0));
    Gen g2 = issue_point(x, srd, t + 2 * NT);
    store_out(out, t + NT, consume_point(g1));
    Gen g3 = issue_point(x, srd, t + 3 * NT);
    store_out(out, t + 2 * NT, consume_point(g2));
    store_out(out, t + 3 * NT, consume_point(g3));
}

// ---- Fallback (fp32 direct, grid-stride, 1 pt/thread) if ws too small ----
__global__ __launch_bounds__(256) void featurefield_fp32_kernel(
    const float* __restrict__ x,
    const float2* __restrict__ table,
    f32x2* __restrict__ out,
    int n_points)
{
    int p = blockIdx.x * blockDim.x + threadIdx.x;
    if (p >= n_points) return;

    float xs = x[3 * p + 0] * RES_F;
    float ys = x[3 * p + 1] * RES_F;
    float zs = x[3 * p + 2] * RES_F;
    float fxf = floorf(xs), fyf = floorf(ys), fzf = floorf(zs);
    int fx = (int)fxf, fy = (int)fyf, fz = (int)fzf;
    int cx = (int)ceilf(xs), cy = (int)ceilf(ys), cz = (int)ceilf(zs);
    float dx = xs - fxf, dy = ys - fyf, dz = zs - fzf;
    uint32_t ufx = (uint32_t)fx, ucx = (uint32_t)cx;
    uint32_t fyp = (uint32_t)fy * 2654435761u, cyp = (uint32_t)cy * 2654435761u;
    uint32_t fzp = (uint32_t)fz * 805459861u, czp = (uint32_t)cz * 805459861u;
    uint32_t h0 = (ufx ^ fyp ^ fzp) & HASHTABLE_MASK;
    uint32_t h1 = (ucx ^ fyp ^ fzp) & HASHTABLE_MASK;
    uint32_t h2 = (ufx ^ cyp ^ fzp) & HASHTABLE_MASK;
    uint32_t h3 = (ufx ^ fyp ^ czp) & HASHTABLE_MASK;
    uint32_t h4 = (ucx ^ cyp ^ fzp) & HASHTABLE_MASK;
    uint32_t h5 = (ucx ^ fyp ^ czp) & HASHTABLE_MASK;
    uint32_t h6 = (ufx ^ cyp ^ czp) & HASHTABLE_MASK;
    uint32_t h7 = (ucx ^ cyp ^ czp) & HASHTABLE_MASK;

    float2 v0 = table[h0], v1 = table[h1], v2 = table[h2], v3 = table[h3];
    float2 v4 = table[h4], v5 = table[h5], v6 = table[h6], v7 = table[h7];

    float wx = 1.0f - dx, wy = 1.0f - dy, wz = 1.0f - dz;
    float c00x = v0.x * wx + v1.x * dx, c00y = v0.y * wx + v1.y * dx;
    float c01x = v3.x * wx + v5.x * dx, c01y = v3.y * wx + v5.y * dx;
    float c10x = v2.x * wx + v4.x * dx, c10y = v2.y * wx + v4.y * dx;
    float c11x = v6.x * wx + v7.x * dx, c11y = v6.y * wx + v7.y * dx;
    float c0x = c00x * wy + c10x * dy, c0y = c00y * wy + c10y * dy;
    float c1x = c01x * wy + c11x * dy, c1y = c01y * wy + c11y * dy;

    f32x2 r;
    r.x = c0x * wz + c1x * dz;
    r.y = c0y * wz + c1y * dz;
    __builtin_nontemporal_store(r, out + p);
}

extern "C" void kernel_launch(void* const* d_in, const int* in_sizes, int n_in,
                              void* d_out, int out_size, void* d_ws, size_t ws_size,
                              hipStream_t stream) {
    const float* x = (const float*)d_in[0];
    f32x2* out = (f32x2*)d_out;

    int n_points = in_sizes[0] / 3;   // 4194304
    size_t need = (size_t)HASHTABLE_SIZE * 4u;   // 2 MiB bf16 table

    if (ws_size >= need && (n_points & 3) == 0) {
        const f32x4* table4 = (const f32x4*)d_in[1];
        u32x4* ws4 = (u32x4*)d_ws;
        int conv_threads = HASHTABLE_SIZE / 4;   // 131072
        convert_table_kernel<<<conv_threads / 256, 256, 0, stream>>>(table4, ws4);

        int NT = n_points / 4;                   // 1048576
        int grid = (NT + 255) / 256;             // 4096
        featurefield_pipe_kernel<<<grid, 256, 0, stream>>>(
            x, (const uint32_t*)d_ws, out, NT);
    } else {
        const float2* table = (const float2*)d_in[1];
        int grid = (n_points + 255) / 256;
        featurefield_fp32_kernel<<<grid, 256, 0, stream>>>(x, table, out, n_points);
    }
}

// Round 9
// 176.340 us; speedup vs baseline: 1.1027x; 1.0199x over previous
//
#include <hip/hip_runtime.h>
#include <stdint.h>

#define LOG2_HASHMAP_SIZE 19
#define HASHTABLE_SIZE (1u << LOG2_HASHMAP_SIZE)
#define HASHTABLE_MASK (HASHTABLE_SIZE - 1u)
#define RES_F 128.0f

typedef float f32x2 __attribute__((ext_vector_type(2)));
typedef float f32x4 __attribute__((ext_vector_type(4)));
typedef uint32_t u32x4 __attribute__((ext_vector_type(4)));
typedef int i32x4 __attribute__((ext_vector_type(4)));

// Raw buffer loads: SRD base in SGPRs -> 1 VGPR (voffset) per gather.
__device__ u32x4 llvm_amdgcn_raw_buffer_load_v4u32(i32x4 rsrc, int voffset,
                                                   int soffset, int aux)
    __asm("llvm.amdgcn.raw.buffer.load.v4i32");
__device__ uint32_t llvm_amdgcn_raw_buffer_load_u32(i32x4 rsrc, int voffset,
                                                    int soffset, int aux)
    __asm("llvm.amdgcn.raw.buffer.load.i32");

__device__ __forceinline__ i32x4 make_srd(const void* p, uint32_t bytes) {
    union { const void* p; uint32_t u[2]; } a;
    a.p = p;
    i32x4 r;
    r.x = (int)a.u[0];                 // base[31:0]
    r.y = (int)(a.u[1] & 0xFFFFu);     // base[47:32], stride=0
    r.z = (int)bytes;                  // num_records (bytes, stride==0)
    r.w = 0x00020000;                  // raw untyped dword access
    return r;
}

__device__ __forceinline__ float bf16w_lo(uint32_t w) {
    return __uint_as_float(w << 16);
}
__device__ __forceinline__ float bf16w_hi(uint32_t w) {
    return __uint_as_float(w & 0xFFFF0000u);
}

// Select one of 4 packed words by 2-bit index (explicit cndmask chain).
__device__ __forceinline__ uint32_t sel4(u32x4 q, uint32_t e) {
    uint32_t lo = (e & 1u) ? q.y : q.x;
    uint32_t hi = (e & 1u) ? q.w : q.z;
    return (e & 2u) ? hi : lo;
}

// ---- Pass 1: convert fp32 table (float2/entry) -> bf16x2 (uint32/entry) ----
__device__ __forceinline__ uint32_t pack_bf16x2(float a, float b) {
    uint32_t ua = __float_as_uint(a);
    uint32_t ub = __float_as_uint(b);
    ua = ua + 0x7FFFu + ((ua >> 16) & 1u);   // RTNE
    ub = ub + 0x7FFFu + ((ub >> 16) & 1u);
    return (ua >> 16) | (ub & 0xFFFF0000u);
}

__global__ __launch_bounds__(256) void convert_table_kernel(
    const f32x4* __restrict__ table4,   // HASHTABLE_SIZE/2 float4 (2 entries each)
    u32x4* __restrict__ ws4)            // HASHTABLE_SIZE/4 uint4
{
    int i = blockIdx.x * blockDim.x + threadIdx.x;   // 1 uint4 = 4 entries
    f32x4 e01 = table4[2 * i + 0];
    f32x4 e23 = table4[2 * i + 1];
    u32x4 o;
    o.x = pack_bf16x2(e01.x, e01.y);
    o.y = pack_bf16x2(e01.z, e01.w);
    o.z = pack_bf16x2(e23.x, e23.y);
    o.w = pack_bf16x2(e23.z, e23.w);
    ws4[i] = o;
}

// ---- Pass 2: main kernel with LDS-compacted partner loads ----
// R6 granule scheme: per point 4 x 16B always-loads (each covers both
// x-corners of a yz-pair when mm<=3, 75% of points). The 25% far points
// (mm>3) need 4 extra 4B partner loads — instead of per-lane MASKED load
// instructions (which cost full TA slots), far threads append partner
// indices to an LDS queue; after a barrier all 256 threads drain the queue
// with FULL-EXEC loads. Wave gather-instruction slots/pt: 8 -> ~5.
__global__ __launch_bounds__(256) void featurefield_cmp_kernel(
    const float* __restrict__ x,        // N*3 floats
    const uint32_t* __restrict__ tb,    // HASHTABLE_SIZE bf16x2 entries
    f32x2* __restrict__ out,            // N float2
    int n_points)
{
    __shared__ uint32_t s_queue[1024];    // entry: idx(19) | (slot*4+j stored as pos)
    __shared__ uint32_t s_res[1024];
    __shared__ uint32_t s_cnt;

    int tid = threadIdx.x;
    int p = blockIdx.x * blockDim.x + tid;

    if (tid == 0) s_cnt = 0;

    i32x4 srd = make_srd(tb, HASHTABLE_SIZE * 4u);

    float xs = __builtin_nontemporal_load(x + 3 * p + 0) * RES_F;
    float ys = __builtin_nontemporal_load(x + 3 * p + 1) * RES_F;
    float zs = __builtin_nontemporal_load(x + 3 * p + 2) * RES_F;

    float fxf = floorf(xs), fyf = floorf(ys), fzf = floorf(zs);
    int fx = (int)fxf, fy = (int)fyf, fz = (int)fzf;
    int cx = (int)ceilf(xs), cy = (int)ceilf(ys), cz = (int)ceilf(zs);
    float dx = xs - fxf, dy = ys - fyf, dz = zs - fzf;

    uint32_t ufx = (uint32_t)fx;
    uint32_t mm = ufx ^ (uint32_t)cx;
    uint32_t fyp = (uint32_t)fy * 2654435761u;
    uint32_t cyp = (uint32_t)cy * 2654435761u;
    uint32_t fzp = (uint32_t)fz * 805459861u;
    uint32_t czp = (uint32_t)cz * 805459861u;

    uint32_t i0[4];
    i0[0] = (ufx ^ fyp ^ fzp) & HASHTABLE_MASK;  // (fy,fz)
    i0[1] = (ufx ^ cyp ^ fzp) & HASHTABLE_MASK;  // (cy,fz)
    i0[2] = (ufx ^ fyp ^ czp) & HASHTABLE_MASK;  // (fy,cz)
    i0[3] = (ufx ^ cyp ^ czp) & HASHTABLE_MASK;  // (cy,cz)

    // Always-loads issued first: in flight across the compaction barriers.
    u32x4 q[4];
    #pragma unroll
    for (int j = 0; j < 4; ++j) {
        q[j] = llvm_amdgcn_raw_buffer_load_v4u32(
            srd, (int)((i0[j] << 2) & ~15u), 0, 0);
    }

    __syncthreads();   // s_cnt = 0 visible

    // Far points enqueue their 4 partner indices.
    uint32_t base = 0;
    bool far = (mm > 3u);
    if (far) {
        base = atomicAdd(&s_cnt, 4u);
        #pragma unroll
        for (int j = 0; j < 4; ++j) {
            s_queue[base + j] = (i0[j] ^ mm);
        }
    }

    __syncthreads();

    // Drain the queue with full-exec gather instructions.
    uint32_t Q = s_cnt;
    for (uint32_t i = tid; i < Q; i += 256u) {
        uint32_t idx = s_queue[i];
        s_res[i] = llvm_amdgcn_raw_buffer_load_u32(srd, (int)(idx << 2), 0, 0);
    }

    __syncthreads();

    // Extraction: near points pull both corners from the granule; far points
    // read partners from LDS.
    uint32_t w0[4], w1[4];
    #pragma unroll
    for (int j = 0; j < 4; ++j) {
        uint32_t e0 = i0[j] & 3u;
        w0[j] = sel4(q[j], e0);
        w1[j] = far ? s_res[base + j] : sel4(q[j], e0 ^ mm);
    }

    // Trilinear interpolation, reference ordering.
    float wx = 1.0f - dx, wy = 1.0f - dy, wz = 1.0f - dz;

    // pair j: 0=(fy,fz) 1=(cy,fz) 2=(fy,cz) 3=(cy,cz); w0=fx, w1=cx
    float c00x = bf16w_lo(w0[0]) * wx + bf16w_lo(w1[0]) * dx;
    float c00y = bf16w_hi(w0[0]) * wx + bf16w_hi(w1[0]) * dx;
    float c10x = bf16w_lo(w0[1]) * wx + bf16w_lo(w1[1]) * dx;
    float c10y = bf16w_hi(w0[1]) * wx + bf16w_hi(w1[1]) * dx;
    float c01x = bf16w_lo(w0[2]) * wx + bf16w_lo(w1[2]) * dx;
    float c01y = bf16w_hi(w0[2]) * wx + bf16w_hi(w1[2]) * dx;
    float c11x = bf16w_lo(w0[3]) * wx + bf16w_lo(w1[3]) * dx;
    float c11y = bf16w_hi(w0[3]) * wx + bf16w_hi(w1[3]) * dx;

    float c0x = c00x * wy + c10x * dy;
    float c0y = c00y * wy + c10y * dy;
    float c1x = c01x * wy + c11x * dy;
    float c1y = c01y * wy + c11y * dy;

    f32x2 r;
    r.x = c0x * wz + c1x * dz;
    r.y = c0y * wz + c1y * dz;
    __builtin_nontemporal_store(r, out + p);
}

// ---- Fallback (fp32 direct, 1 pt/thread) if ws too small ----
__global__ __launch_bounds__(256) void featurefield_fp32_kernel(
    const float* __restrict__ x,
    const float2* __restrict__ table,
    f32x2* __restrict__ out,
    int n_points)
{
    int p = blockIdx.x * blockDim.x + threadIdx.x;
    if (p >= n_points) return;

    float xs = x[3 * p + 0] * RES_F;
    float ys = x[3 * p + 1] * RES_F;
    float zs = x[3 * p + 2] * RES_F;
    float fxf = floorf(xs), fyf = floorf(ys), fzf = floorf(zs);
    int fx = (int)fxf, fy = (int)fyf, fz = (int)fzf;
    int cx = (int)ceilf(xs), cy = (int)ceilf(ys), cz = (int)ceilf(zs);
    float dx = xs - fxf, dy = ys - fyf, dz = zs - fzf;
    uint32_t ufx = (uint32_t)fx, ucx = (uint32_t)cx;
    uint32_t fyp = (uint32_t)fy * 2654435761u, cyp = (uint32_t)cy * 2654435761u;
    uint32_t fzp = (uint32_t)fz * 805459861u, czp = (uint32_t)cz * 805459861u;
    uint32_t h0 = (ufx ^ fyp ^ fzp) & HASHTABLE_MASK;
    uint32_t h1 = (ucx ^ fyp ^ fzp) & HASHTABLE_MASK;
    uint32_t h2 = (ufx ^ cyp ^ fzp) & HASHTABLE_MASK;
    uint32_t h3 = (ufx ^ fyp ^ czp) & HASHTABLE_MASK;
    uint32_t h4 = (ucx ^ cyp ^ fzp) & HASHTABLE_MASK;
    uint32_t h5 = (ucx ^ fyp ^ czp) & HASHTABLE_MASK;
    uint32_t h6 = (ufx ^ cyp ^ czp) & HASHTABLE_MASK;
    uint32_t h7 = (ucx ^ cyp ^ czp) & HASHTABLE_MASK;

    float2 v0 = table[h0], v1 = table[h1], v2 = table[h2], v3 = table[h3];
    float2 v4 = table[h4], v5 = table[h5], v6 = table[h6], v7 = table[h7];

    float wx = 1.0f - dx, wy = 1.0f - dy, wz = 1.0f - dz;
    float c00x = v0.x * wx + v1.x * dx, c00y = v0.y * wx + v1.y * dx;
    float c01x = v3.x * wx + v5.x * dx, c01y = v3.y * wx + v5.y * dx;
    float c10x = v2.x * wx + v4.x * dx, c10y = v2.y * wx + v4.y * dx;
    float c11x = v6.x * wx + v7.x * dx, c11y = v6.y * wx + v7.y * dx;
    float c0x = c00x * wy + c10x * dy, c0y = c00y * wy + c10y * dy;
    float c1x = c01x * wy + c11x * dy, c1y = c01y * wy + c11y * dy;

    f32x2 r;
    r.x = c0x * wz + c1x * dz;
    r.y = c0y * wz + c1y * dz;
    __builtin_nontemporal_store(r, out + p);
}

extern "C" void kernel_launch(void* const* d_in, const int* in_sizes, int n_in,
                              void* d_out, int out_size, void* d_ws, size_t ws_size,
                              hipStream_t stream) {
    const float* x = (const float*)d_in[0];
    f32x2* out = (f32x2*)d_out;

    int n_points = in_sizes[0] / 3;   // 4194304
    size_t need = (size_t)HASHTABLE_SIZE * 4u;   // 2 MiB bf16 table

    if (ws_size >= need && (n_points & 255) == 0) {
        const f32x4* table4 = (const f32x4*)d_in[1];
        u32x4* ws4 = (u32x4*)d_ws;
        int conv_threads = HASHTABLE_SIZE / 4;   // 131072
        convert_table_kernel<<<conv_threads / 256, 256, 0, stream>>>(table4, ws4);

        int grid = n_points / 256;               // 16384
        featurefield_cmp_kernel<<<grid, 256, 0, stream>>>(
            x, (const uint32_t*)d_ws, out, n_points);
    } else {
        const float2* table = (const float2*)d_in[1];
        int grid = (n_points + 255) / 256;
        featurefield_fp32_kernel<<<grid, 256, 0, stream>>>(x, table, out, n_points);
    }
}